// Round 6
// baseline (504.100 us; speedup 1.0000x reference)
//
#include <hip/hip_runtime.h>
#include <hip/hip_bf16.h>
#include <stdint.h>
#include <math.h>

#define D_MODEL 768
#define HEADS 12
#define D_HEAD 64
#define BATCH 16
#define SP 256
#define SI 1024
#define NP (BATCH * SP)   // 4096 prompt rows
#define NI (BATCH * SI)   // 16384 image rows

#define GLOBAL_AS __attribute__((address_space(1)))
#define LDS_AS    __attribute__((address_space(3)))

typedef __attribute__((ext_vector_type(8))) short  frag_ab;  // 8 bf16 (4 VGPRs)
typedef __attribute__((ext_vector_type(4))) float  frag_cd;  // 4 fp32 acc

static __device__ __forceinline__ ushort f2bf(float f) {
  __hip_bfloat16 h = __float2bfloat16(f);
  return *(ushort*)&h;
}
static __device__ __forceinline__ float bf2f(ushort u) {
  return __bfloat162float(*(__hip_bfloat16*)&u);
}
// dtype hedge (round-1 verified: bf16). ln_p1_g all-ones word0 probe.
static __device__ __forceinline__ bool probe_bf(const uint32_t* p) {
  return p[0] == 0x3F803F80u;
}

// ---------------------------------------------------------------------------
// prep: z<10 -> weight transpose [k][n]->[n][k] bf16 ; z==10 -> convert the
// 18 param vectors (10 biases + 8 LN g/b) to fp32 (contiguous dst).
// ---------------------------------------------------------------------------
struct Prep {
  const void* wsrc[10]; ushort* wdst[10];
  const void* vsrc[18]; float* vdst;   // 18 x 768 fp32, contiguous
};

__global__ __launch_bounds__(256) void prep_kernel(Prep p, const uint32_t* probe) {
  const bool isbf = probe_bf(probe);
  const int z = blockIdx.z;
  if (z < 10) {
    __shared__ float tile[32][33];
    const int tx = threadIdx.x & 31, ty = threadIdx.x >> 5;
    const int x0 = blockIdx.x * 32, y0 = blockIdx.y * 32;
    const void* src = p.wsrc[z];
    ushort* dst = p.wdst[z];
#pragma unroll
    for (int i = 0; i < 4; i++) {
      const int y = y0 + ty + i * 8;
      float v;
      if (isbf) v = bf2f(((const ushort*)src)[(size_t)y * 768 + x0 + tx]);
      else      v = ((const float*)src)[(size_t)y * 768 + x0 + tx];
      tile[ty + i * 8][tx] = v;
    }
    __syncthreads();
#pragma unroll
    for (int i = 0; i < 4; i++) {
      const int row = x0 + ty + i * 8;   // n
      const int col = y0 + tx;           // k
      dst[(size_t)row * 768 + col] = f2bf(tile[tx][ty + i * 8]);
    }
  } else {
    const int idx = (blockIdx.y * 24 + blockIdx.x) * 256 + threadIdx.x;
    if (idx < 18 * 768) {
      const int e = idx / 768, i = idx - e * 768;
      float v;
      if (isbf) v = bf2f(((const ushort*)p.vsrc[e])[i]);
      else      v = ((const float*)p.vsrc[e])[i];
      p.vdst[idx] = v;
    }
  }
}

// ---------------------------------------------------------------------------
// add+LN, wave-per-row: 4 rows/block (1 wave each), no LDS, no barriers.
// Lane owns 12 elems: {k*256 + lane*4 ..+3}, k=0..2. (sum,sumsq) via 6-step
// __shfl_xor butterfly. Math identical to original verified add_ln2.
// ---------------------------------------------------------------------------
struct LNJob {
  const void* a; const void* b;
  const float* g; const float* be;
  float* sum_out; ushort* ln_out;
  int nrows; int abf;
};

__global__ __launch_bounds__(256) void add_ln_wave(LNJob J0, LNJob J1, const uint32_t* probe) {
  const int w = threadIdx.x >> 6, lane = threadIdx.x & 63;
  int row = blockIdx.x * 4 + w;
  LNJob j = (row < J0.nrows) ? J0 : J1;
  if (row >= J0.nrows) row -= J0.nrows;
  if (row >= j.nrows) return;
  const size_t base = (size_t)row * D_MODEL;
  const bool isbf = j.abf && probe_bf(probe);
  float x[12];
#pragma unroll
  for (int k = 0; k < 3; k++) {
    const int c = k * 256 + lane * 4;
    if (isbf) {
      const uint2 ua = *(const uint2*)((const ushort*)j.a + base + c);
      const uint2 ub = *(const uint2*)((const ushort*)j.b + base + c);
      const ushort* pa = (const ushort*)&ua;
      const ushort* pb = (const ushort*)&ub;
#pragma unroll
      for (int t = 0; t < 4; t++) x[k * 4 + t] = bf2f(pa[t]) + bf2f(pb[t]);
    } else {
      const float4 fa = *(const float4*)((const float*)j.a + base + c);
      const float4 fb = *(const float4*)((const float*)j.b + base + c);
      x[k * 4 + 0] = fa.x + fb.x; x[k * 4 + 1] = fa.y + fb.y;
      x[k * 4 + 2] = fa.z + fb.z; x[k * 4 + 3] = fa.w + fb.w;
    }
    if (j.sum_out) {
      float4 s4;
      s4.x = x[k * 4 + 0]; s4.y = x[k * 4 + 1];
      s4.z = x[k * 4 + 2]; s4.w = x[k * 4 + 3];
      *(float4*)&j.sum_out[base + c] = s4;
    }
  }
  float s = 0.f, q = 0.f;
#pragma unroll
  for (int t = 0; t < 12; t++) { s += x[t]; q += x[t] * x[t]; }
#pragma unroll
  for (int o = 32; o > 0; o >>= 1) { s += __shfl_xor(s, o); q += __shfl_xor(q, o); }
  const float mu  = s * (1.0f / D_MODEL);
  const float var = q * (1.0f / D_MODEL) - mu * mu;
  const float inv = rsqrtf(var + 1e-5f);
#pragma unroll
  for (int k = 0; k < 3; k++) {
    const int c = k * 256 + lane * 4;
    const float4 gv = *(const float4*)&j.g[c];
    const float4 bv = *(const float4*)&j.be[c];
    uint2 ou;
    ushort* oe = (ushort*)&ou;
    oe[0] = f2bf((x[k * 4 + 0] - mu) * inv * gv.x + bv.x);
    oe[1] = f2bf((x[k * 4 + 1] - mu) * inv * gv.y + bv.y);
    oe[2] = f2bf((x[k * 4 + 2] - mu) * inv * gv.z + bv.z);
    oe[3] = f2bf((x[k * 4 + 3] - mu) * inv * gv.w + bv.w);
    *(uint2*)(j.ln_out + base + c) = ou;
  }
}

// ---------------------------------------------------------------------------
// Shared 128x128 BK=64 4-fat-phase engine, round-5: ONE barrier per phase
// (was two). LDS: lds[slot(2)][{A,B}(2)][128*64 bf16] = 64 KiB -> 2 blk/CU.
// Swizzle: phys 16B-chunk = logical chunk ^ (row&7); staging pre-swizzles the
// GLOBAL source column (linear LDS dest, rule #21); ds_read XORs the same.
//
// Phase p: { RD(slot) ; STAGE(other region) ; LGKM0 ; 16 MFMA ; [VMC4] ; BAR }
// Hazard inventory for the single barrier (all verified by ledger):
//  - overwrite: STAGE(p) targets the region last read in p-1; those reads
//    completed at each wave's LGKM0(p-1), which precedes BAR(p-1); STAGE(p)
//    issues after BAR(p-1).  [cross-wave safe]
//  - data-ready: vmcnt is per-wave, but all waves run the identical load
//    schedule and VMC4 sits immediately BEFORE the end-of-phase BAR at P2/P4,
//    so at that barrier every wave's loads older than its newest 4 are
//    complete -> collectively complete before any dependent read.
// vmcnt ledger (4 loads/thread/region): outstanding at VMC4(P2) =
// prevP4(4)+P1(4)+P2(4)=12 -> wait to 4 -> slot1 A+B landed for P3; at
// VMC4(P4): P2(4)+P3(4)+P4(4)=12 -> 4 -> slot0 A+B landed for next P1.
// Never vmcnt(0) in loop. Last iters clamp prefetch tile to 11 (valid
// address, lands in dead regions).
// ---------------------------------------------------------------------------
#define BAR   __builtin_amdgcn_s_barrier()
#define LGKM0 do { asm volatile("s_waitcnt lgkmcnt(0)" ::: "memory"); \
                   __builtin_amdgcn_sched_barrier(0); } while (0)
#define VMC4  do { asm volatile("s_waitcnt vmcnt(4)" ::: "memory"); \
                   __builtin_amdgcn_sched_barrier(0); } while (0)

#define RD_A(SL) do { \
  const ushort* _b = &lds[SL][0][0]; \
  _Pragma("unroll") for (int _m = 0; _m < 4; ++_m) \
  _Pragma("unroll") for (int _k = 0; _k < 2; ++_k) \
    aF[_m][_k] = *(const frag_ab*)(_b + ((wr << 6) + _m * 16 + ml) * 64 + \
                                   (((_k << 5) + (kq << 3)) ^ swz)); \
} while (0)

#define RD_B(DST, SL, no) do { \
  const ushort* _b = &lds[SL][1][0]; \
  _Pragma("unroll") for (int _n = 0; _n < 2; ++_n) \
  _Pragma("unroll") for (int _k = 0; _k < 2; ++_k) \
    DST[_n][_k] = *(const frag_ab*)(_b + ((wc << 6) + (no) + _n * 16 + ml) * 64 + \
                                    (((_k << 5) + (kq << 3)) ^ swz)); \
} while (0)

#define MM(NB, BF) do { \
  __builtin_amdgcn_s_setprio(1); \
  _Pragma("unroll") for (int _m = 0; _m < 4; ++_m) \
  _Pragma("unroll") for (int _n = 0; _n < 2; ++_n) \
  _Pragma("unroll") for (int _k = 0; _k < 2; ++_k) \
    acc[_m][(NB) + _n] = __builtin_amdgcn_mfma_f32_16x16x32_bf16( \
        aF[_m][_k], BF[_n][_k], acc[_m][(NB) + _n], 0, 0, 0); \
  __builtin_amdgcn_s_setprio(0); \
} while (0)

#define STAGE(SL, RG, PTR, RBASE, KT) do { \
  const ushort* _p = (PTR) + (size_t)((RBASE) + srow) * 768 + ((KT) << 6) + scol; \
  _Pragma("unroll") for (int _j = 0; _j < 4; ++_j) \
    __builtin_amdgcn_global_load_lds( \
        (const GLOBAL_AS void*)(_p + (size_t)(_j * 32) * 768), \
        (LDS_AS void*)((LDS_AS ushort*)&lds[SL][RG][0] + (((_j << 2) + w) << 9)), \
        16, 0, 0); \
} while (0)

#define ENGINE128() do { \
  STAGE(0, 0, jA, m0, 0); \
  STAGE(0, 1, jB, n0, 0); \
  STAGE(1, 0, jA, m0, 1); \
  VMC4; BAR; \
  for (int it = 0; it < 6; ++it) { \
    const int t1  = 2 * it + 1; \
    const int tn0 = (2 * it + 2 < 12) ? 2 * it + 2 : 11; \
    const int tn1 = (2 * it + 3 < 12) ? 2 * it + 3 : 11; \
    /* P1 */ \
    RD_A(0); RD_B(bF0, 0, 0); \
    STAGE(1, 1, jB, n0, t1); \
    LGKM0; \
    MM(0, bF0); \
    BAR; \
    /* P2 */ \
    RD_B(bF1, 0, 32); \
    STAGE(0, 0, jA, m0, tn0); \
    LGKM0; \
    MM(2, bF1); \
    VMC4; BAR; \
    /* P3 */ \
    RD_A(1); RD_B(bF0, 1, 0); \
    STAGE(0, 1, jB, n0, tn0); \
    LGKM0; \
    MM(0, bF0); \
    BAR; \
    /* P4 */ \
    RD_B(bF1, 1, 32); \
    STAGE(1, 0, jA, m0, tn1); \
    LGKM0; \
    MM(2, bF1); \
    VMC4; BAR; \
  } \
} while (0)

// ---------------------------------------------------------------------------
// Mega GEMM (round-2 verified routing): engine + o0/o1/vT routing epilogue.
// ---------------------------------------------------------------------------
struct GJob {
  const ushort* A; const ushort* Bt; const float* bias;
  ushort* o0; ushort* o1; ushort* vT;
  int X; int vsub; int shift;
};

__global__ __launch_bounds__(256, 2) void gemm_mega128(GJob J0, GJob J1, int n0blocks) {
  __shared__ __align__(16) ushort lds[2][2][8192];   // 64 KiB -> 2 blocks/CU
  int bid = blockIdx.x;
  GJob j = (bid < n0blocks) ? J0 : J1;
  if (bid >= n0blocks) bid -= n0blocks;
  const int tid  = threadIdx.x;
  const int lane = tid & 63, w = tid >> 6;
  const int wr = w >> 1, wc = w & 1;
  const int ml = lane & 15, kq = lane >> 4;
  const int rest = bid >> 3;
  const int x = rest % j.X, y = (bid & 7) + 8 * (rest / j.X);
  const int m0 = y << 7, n0 = x << 7;
  // staging: thread covers region rows {srow, srow+32, srow+64, srow+96};
  // (row&7)==(lane>>3) for all four, so one pre-swizzled source column works.
  const int srow = (w << 3) + (lane >> 3);
  const int scol = (((lane & 7) ^ (lane >> 3)) << 3);
  const int swz  = (ml & 7) << 3;
  const ushort* jA = j.A;
  const ushort* jB = j.Bt;

  frag_cd acc[4][4] = {};
  frag_ab aF[4][2], bF0[2][2], bF1[2][2];

  ENGINE128();

  // epilogue: identical routing to round-0 verified 128^2 mega.
  const int sub  = x / 6;                  // 768/128 = 6 tiles per sub-block
  const int mask = (1 << j.shift) - 1;
#pragma unroll
  for (int mt = 0; mt < 4; mt++) {
#pragma unroll
    for (int nt = 0; nt < 4; nt++) {
      const int row0 = m0 + wr * 64 + mt * 16 + kq * 4;
      const int col  = n0 + wc * 64 + nt * 16 + ml;
      const float bc = j.bias[col];
      if (sub == j.vsub) {
        const int hcol = col - sub * 768;
        const int hh = hcol >> 6, dd = hcol & 63;
        const int bb = row0 >> j.shift;
        const int jj = row0 & mask;
        uint2 pack;
        ushort* pe = (ushort*)&pack;
#pragma unroll
        for (int r = 0; r < 4; r++) pe[r] = f2bf(acc[mt][nt][r] + bc);
        *(uint2*)(j.vT + ((((size_t)(bb * HEADS + hh) << 6) + dd) << j.shift) + jj) = pack;
      } else {
        ushort* out = (sub == 0) ? j.o0 : j.o1;
        const int cl = col - sub * 768;
#pragma unroll
        for (int r = 0; r < 4; r++)
          out[(size_t)(row0 + r) * 768 + cl] = f2bf(acc[mt][nt][r] + bc);
      }
    }
  }
}

// ---------------------------------------------------------------------------
// gemm_v3: same engine, flexible epilogue (the 4096x768x768 projections).
// rmode: 0 none, 1 fp32 resid, 2 resid dtype per probe.
// omode: 0 fp32 out, 1 bf16 out, 2 out dtype per probe.
// ---------------------------------------------------------------------------
__global__ __launch_bounds__(256, 2) void gemm_v3(
    const ushort* __restrict__ A, const ushort* __restrict__ Bt,
    const float* __restrict__ bias,
    const void* __restrict__ resid, int rmode,
    void* __restrict__ C, int relu, int omode,
    const uint32_t* __restrict__ probe, int X) {
  __shared__ __align__(16) ushort lds[2][2][8192];   // 64 KiB
  const int bid = blockIdx.x;
  const int tid  = threadIdx.x;
  const int lane = tid & 63, w = tid >> 6;
  const int wr = w >> 1, wc = w & 1;
  const int ml = lane & 15, kq = lane >> 4;
  const int rest = bid >> 3;
  const int x = rest % X, y = (bid & 7) + 8 * (rest / X);
  const int m0 = y << 7, n0 = x << 7;
  const int srow = (w << 3) + (lane >> 3);
  const int scol = (((lane & 7) ^ (lane >> 3)) << 3);
  const int swz  = (ml & 7) << 3;
  const ushort* jA = A;
  const ushort* jB = Bt;

  frag_cd acc[4][4] = {};
  frag_ab aF[4][2], bF0[2][2], bF1[2][2];

  ENGINE128();

  const bool obf = (omode == 1) || (omode == 2 && probe_bf(probe));
  const bool rbf = (rmode == 2) && probe_bf(probe);
#pragma unroll
  for (int mt = 0; mt < 4; mt++) {
#pragma unroll
    for (int nt = 0; nt < 4; nt++) {
      const int row0 = m0 + wr * 64 + mt * 16 + kq * 4;
      const int col  = n0 + wc * 64 + nt * 16 + ml;
      const float bc = bias[col];
#pragma unroll
      for (int r = 0; r < 4; r++) {
        const size_t off = (size_t)(row0 + r) * 768 + col;
        float v = acc[mt][nt][r] + bc;
        if (rmode != 0)
          v += rbf ? bf2f(((const ushort*)resid)[off]) : ((const float*)resid)[off];
        if (relu) v = fmaxf(v, 0.f);
        if (obf) ((ushort*)C)[off] = f2bf(v);
        else     ((float*)C)[off]  = v;
      }
    }
  }
}

#undef RD_A
#undef RD_B
#undef MM
#undef STAGE
#undef ENGINE128

// ---------------------------------------------------------------------------
// MFMA flash attention (round-4 verified): double-buffered K/V LDS -> ONE
// barrier per KV-tile, + T14 reg prefetch. Iter t: prefetch tile t+1 -> regs;
// compute QK/softmax/PV from buf c=t&1; write regs -> buf c^1; barrier.
// LDS 52 KB -> 3 blocks/CU = one full round of 768 blocks.
// ---------------------------------------------------------------------------
#define FS 68
__global__ __launch_bounds__(256) void fattn_mfma(
    const ushort* __restrict__ Q, const ushort* __restrict__ Kp,
    const ushort* __restrict__ vT, ushort* __restrict__ O, int Skv) {
  __shared__ __align__(16) ushort Qs[64 * FS];
  __shared__ __align__(16) ushort Ks[2][64 * FS];
  __shared__ __align__(16) ushort Vt[2][64 * FS];
  __shared__ __align__(16) ushort Ps[64 * FS];
  const int tid  = threadIdx.x;
  const int lane = tid & 63, w = tid >> 6;
  const int ml   = lane & 15, kq = lane >> 4;
  const int bid = blockIdx.x;
  const int g8  = bid & 7;
  const int qt  = (bid >> 3) & 3;
  const int g   = (bid >> 5) * 8 + g8;      // 0..191 = b*12+h
  const int h   = g % HEADS;
  const int b   = g / HEADS;
  const int q0  = qt * 64;
  const ushort* Qb  = Q  + ((size_t)b * SP + q0) * D_MODEL + h * D_HEAD;
  const ushort* Kb  = Kp + (size_t)b * Skv * D_MODEL + h * D_HEAD;
  const ushort* vTb = vT + (size_t)g * 64 * Skv;

  // staging geometry: two 16B chunks per thread, rows r0=tid>>3, r1=r0+32.
  const int r0 = tid >> 3, p0 = tid & 7;
  const int r1 = r0 + 32;

  for (int c = tid; c < 512; c += 256) {
    const int r = c >> 3, p = c & 7;
    *(uint4*)&Qs[r * FS + p * 8] = *(const uint4*)(Qb + (size_t)r * D_MODEL + p * 8);
  }

  // tile 0 -> regs -> buf0
  uint4 kr0 = *(const uint4*)(Kb + (size_t)r0 * D_MODEL + p0 * 8);
  uint4 vr0 = *(const uint4*)(vTb + (size_t)r0 * Skv + p0 * 8);
  uint4 kr1 = *(const uint4*)(Kb + (size_t)r1 * D_MODEL + p0 * 8);
  uint4 vr1 = *(const uint4*)(vTb + (size_t)r1 * Skv + p0 * 8);
  *(uint4*)&Ks[0][r0 * FS + p0 * 8] = kr0;
  *(uint4*)&Vt[0][r0 * FS + p0 * 8] = vr0;
  *(uint4*)&Ks[0][r1 * FS + p0 * 8] = kr1;
  *(uint4*)&Vt[0][r1 * FS + p0 * 8] = vr1;
  __syncthreads();

  frag_ab qa[2];
#pragma unroll
  for (int kc = 0; kc < 2; kc++)
    qa[kc] = *(const frag_ab*)&Qs[(w * 16 + ml) * FS + kc * 32 + kq * 8];

  frag_cd oc[4] = {};
  float m_i[4], l_i[4];
#pragma unroll
  for (int r = 0; r < 4; r++) { m_i[r] = -1e30f; l_i[r] = 0.f; }
  const float SCL = 0.125f * 1.44269504f;
  const int NT = Skv >> 6;

  for (int t = 0; t < NT; ++t) {
    const int cb = t & 1;
    if (t + 1 < NT) {                      // T14: next tile -> regs early
      const int jn = (t + 1) << 6;
      kr0 = *(const uint4*)(Kb + (size_t)(jn + r0) * D_MODEL + p0 * 8);
      vr0 = *(const uint4*)(vTb + (size_t)r0 * Skv + jn + p0 * 8);
      kr1 = *(const uint4*)(Kb + (size_t)(jn + r1) * D_MODEL + p0 * 8);
      vr1 = *(const uint4*)(vTb + (size_t)r1 * Skv + jn + p0 * 8);
    }

    frag_cd sc[4] = {};
#pragma unroll
    for (int nt = 0; nt < 4; nt++)
#pragma unroll
      for (int kc = 0; kc < 2; kc++) {
        const frag_ab bfr = *(const frag_ab*)&Ks[cb][(nt * 16 + ml) * FS + kc * 32 + kq * 8];
        sc[nt] = __builtin_amdgcn_mfma_f32_16x16x32_bf16(qa[kc], bfr, sc[nt], 0, 0, 0);
      }
#pragma unroll
    for (int nt = 0; nt < 4; nt++)
#pragma unroll
      for (int r = 0; r < 4; r++) sc[nt][r] *= SCL;

    float al[4];
#pragma unroll
    for (int r = 0; r < 4; r++) {
      float mx = fmaxf(fmaxf(sc[0][r], sc[1][r]), fmaxf(sc[2][r], sc[3][r]));
#pragma unroll
      for (int m = 1; m < 16; m <<= 1) mx = fmaxf(mx, __shfl_xor(mx, m, 16));
      const float mnew = fmaxf(m_i[r], mx);
      al[r] = exp2f(m_i[r] - mnew);
      float p[4], s = 0.f;
#pragma unroll
      for (int nt = 0; nt < 4; nt++) { p[nt] = exp2f(sc[nt][r] - mnew); s += p[nt]; }
#pragma unroll
      for (int m = 1; m < 16; m <<= 1) s += __shfl_xor(s, m, 16);
      l_i[r] = l_i[r] * al[r] + s;
      m_i[r] = mnew;
      const int prow = (w * 16 + kq * 4 + r) * FS;
#pragma unroll
      for (int nt = 0; nt < 4; nt++) Ps[prow + nt * 16 + ml] = f2bf(p[nt]);
    }
#pragma unroll
    for (int dt = 0; dt < 4; dt++)
#pragma unroll
      for (int r = 0; r < 4; r++) oc[dt][r] *= al[r];

#pragma unroll
    for (int kc = 0; kc < 2; kc++) {
      const frag_ab pa = *(const frag_ab*)&Ps[(w * 16 + ml) * FS + kc * 32 + kq * 8];
#pragma unroll
      for (int dt = 0; dt < 4; dt++) {
        const frag_ab vb = *(const frag_ab*)&Vt[cb][(dt * 16 + ml) * FS + kc * 32 + kq * 8];
        oc[dt] = __builtin_amdgcn_mfma_f32_16x16x32_bf16(pa, vb, oc[dt], 0, 0, 0);
      }
    }

    if (t + 1 < NT) {                      // stage next tile, single barrier
      *(uint4*)&Ks[cb ^ 1][r0 * FS + p0 * 8] = kr0;
      *(uint4*)&Vt[cb ^ 1][r0 * FS + p0 * 8] = vr0;
      *(uint4*)&Ks[cb ^ 1][r1 * FS + p0 * 8] = kr1;
      *(uint4*)&Vt[cb ^ 1][r1 * FS + p0 * 8] = vr1;
      __syncthreads();
    }
  }

  float inv[4];
#pragma unroll
  for (int r = 0; r < 4; r++) inv[r] = 1.0f / l_i[r];
#pragma unroll
  for (int dt = 0; dt < 4; dt++)
#pragma unroll
    for (int r = 0; r < 4; r++)
      O[((size_t)b * SP + q0 + w * 16 + kq * 4 + r) * D_MODEL + h * D_HEAD + dt * 16 + ml] =
          f2bf(oc[dt][r] * inv[r]);
}

// ---------------------------------------------------------------------------
extern "C" void kernel_launch(void* const* d_in, const int* in_sizes, int n_in,
                              void* d_out, int out_size, void* d_ws, size_t ws_size,
                              hipStream_t stream) {
  (void)in_sizes; (void)n_in; (void)out_size;
  char* base = (char*)d_ws;
  size_t off = 256;
  auto alloc = [&](size_t bytes) -> char* {
    char* p = base + off;
    off = (off + bytes + 255) & ~(size_t)255;
    return p;
  };
  const size_t WB = (size_t)768 * 768 * 2;
  ushort* Wt[10];
  for (int i = 0; i < 10; i++) Wt[i] = (ushort*)alloc(WB);   // contiguous
  float* vecs = (float*)alloc(18 * 768 * 4);                 // 10 bias + 8 ln
  float* biasF[10];
  for (int i = 0; i < 10; i++) biasF[i] = vecs + i * 768;
  float* lnF = vecs + 10 * 768;
  float* prompt0 = (float*)alloc((size_t)NP * 768 * 4);
  float* cur     = (float*)alloc((size_t)NP * 768 * 4);
  ushort* q_bf   = (ushort*)alloc((size_t)NP * 768 * 2);
  ushort* k_s    = (ushort*)alloc((size_t)NP * 768 * 2);
  ushort* k_c    = (ushort*)alloc((size_t)NI * 768 * 2);
  ushort* xln_bf = (ushort*)alloc((size_t)NP * 768 * 2);
  ushort* xi_bf  = (ushort*)alloc((size_t)NI * 768 * 2);
  ushort* obuf_bf = (ushort*)alloc((size_t)NP * 768 * 2);
  ushort* ffn1_bf = (ushort*)alloc((size_t)NP * 768 * 2);
  ushort* vT_s   = (ushort*)alloc((size_t)BATCH * HEADS * 64 * SP * 2);
  ushort* vT_c   = (ushort*)alloc((size_t)BATCH * HEADS * 64 * SI * 2);
  if (ws_size < off) return;

  const uint32_t* probe = (const uint32_t*)d_in[4];   // ln_p1_g
  const int widx[10] = {12, 14, 16, 18, 20, 22, 24, 26, 28, 30};
  const int bidx[10] = {13, 15, 17, 19, 21, 23, 25, 27, 29, 31};

  // 1. prep: weight transpose + param convert
  Prep pr{};
  for (int i = 0; i < 10; i++) { pr.wsrc[i] = d_in[widx[i]]; pr.wdst[i] = Wt[i]; }
  for (int i = 0; i < 10; i++) pr.vsrc[i] = d_in[bidx[i]];
  for (int i = 0; i < 8;  i++) pr.vsrc[10 + i] = d_in[4 + i];
  pr.vdst = vecs;
  prep_kernel<<<dim3(24, 24, 11), 256, 0, stream>>>(pr, probe);

  float* G1 = lnF + 0 * 768, *B1 = lnF + 1 * 768;   // ln_p1
  float* G2 = lnF + 2 * 768, *B2 = lnF + 3 * 768;   // ln_p2
  float* G3 = lnF + 4 * 768, *B3 = lnF + 5 * 768;   // ln_p3
  float* Gi = lnF + 6 * 768, *Bi = lnF + 7 * 768;   // ln_i1

  // 2. LN1(prompt+posp, sum->prompt0) + LNi(image+posi) merged, wave-per-row
  LNJob L0{d_in[1], d_in[3], G1, B1, prompt0, xln_bf, NP, 1};
  LNJob Li{d_in[0], d_in[2], Gi, Bi, nullptr, xi_bf,  NI, 1};
  add_ln_wave<<<(NP + NI) / 4, 256, 0, stream>>>(L0, Li, probe);

  // 3. mega GEMM (128x128, 2 blocks/CU): self QKV (576) + cross KV (1536).
  GJob js{xln_bf, Wt[0], biasF[0], q_bf, k_s, vT_s, 18, 2, 8};
  GJob jc{xi_bf,  Wt[5], biasF[5], k_c,  nullptr, vT_c, 12, 1, 10};
  gemm_mega128<<<576 + 1536, 256, 0, stream>>>(js, jc, 576);

  // 4. self flash attention
  fattn_mfma<<<BATCH * HEADS * (SP / 64), 256, 0, stream>>>(q_bf, k_s, vT_s, obuf_bf, SP);

  // 5. O-proj self: cur(fp32) = obuf@Wo + bo + prompt(input dtype)
  gemm_v3<<<192, 256, 0, stream>>>(obuf_bf, Wt[3], biasF[3],
      d_in[1], 2, cur, 0, 0, probe, 6);

  // 6. LN2(cur + prompt0)
  LNJob L2{cur, prompt0, G2, B2, nullptr, xln_bf, NP, 0};
  LNJob Lz{}; Lz.nrows = 0;
  add_ln_wave<<<NP / 4, 256, 0, stream>>>(L2, Lz, probe);

  // 7. cross Q projection (bf16 out)
  gemm_v3<<<192, 256, 0, stream>>>(xln_bf, Wt[4], biasF[4],
      nullptr, 0, q_bf, 0, 1, probe, 6);

  // 8. cross flash attention
  fattn_mfma<<<BATCH * HEADS * (SP / 64), 256, 0, stream>>>(q_bf, k_c, vT_c, obuf_bf, SI);

  // 9. O-proj cross: cur = obuf@Wo2 + bo2 + cur (fp32, in-place per-element)
  gemm_v3<<<192, 256, 0, stream>>>(obuf_bf, Wt[7], biasF[7],
      cur, 1, cur, 0, 0, probe, 6);

  // 10. LN3(cur + prompt0)
  LNJob L3{cur, prompt0, G3, B3, nullptr, xln_bf, NP, 0};
  add_ln_wave<<<NP / 4, 256, 0, stream>>>(L3, Lz, probe);

  // 11. FFN1: relu(xln@W1+b1) -> bf16
  gemm_v3<<<192, 256, 0, stream>>>(xln_bf, Wt[8], biasF[8],
      nullptr, 0, ffn1_bf, 1, 1, probe, 6);

  // 12. FFN2: d_out (dtype per probe)
  gemm_v3<<<192, 256, 0, stream>>>(ffn1_bf, Wt[9], biasF[9],
      nullptr, 0, d_out, 0, 2, probe, 6);
}

// Round 8
// 467.661 us; speedup vs baseline: 1.0779x; 1.0779x over previous
//
#include <hip/hip_runtime.h>
#include <hip/hip_bf16.h>
#include <stdint.h>
#include <math.h>

#define D_MODEL 768
#define HEADS 12
#define D_HEAD 64
#define BATCH 16
#define SP 256
#define SI 1024
#define NP (BATCH * SP)   // 4096 prompt rows
#define NI (BATCH * SI)   // 16384 image rows

#define GLOBAL_AS __attribute__((address_space(1)))
#define LDS_AS    __attribute__((address_space(3)))

typedef __attribute__((ext_vector_type(8))) short  frag_ab;  // 8 bf16 (4 VGPRs)
typedef __attribute__((ext_vector_type(4))) float  frag_cd;  // 4 fp32 acc

static __device__ __forceinline__ ushort f2bf(float f) {
  __hip_bfloat16 h = __float2bfloat16(f);
  return *(ushort*)&h;
}
static __device__ __forceinline__ float bf2f(ushort u) {
  return __bfloat162float(*(__hip_bfloat16*)&u);
}
// dtype hedge (round-1 verified: bf16). ln_p1_g all-ones word0 probe.
static __device__ __forceinline__ bool probe_bf(const uint32_t* p) {
  return p[0] == 0x3F803F80u;
}

// ---------------------------------------------------------------------------
// prep: z<10 -> weight transpose [k][n]->[n][k] bf16 ; z==10 -> convert the
// 18 param vectors (10 biases + 8 LN g/b) to fp32 (contiguous dst).
// ---------------------------------------------------------------------------
struct Prep {
  const void* wsrc[10]; ushort* wdst[10];
  const void* vsrc[18]; float* vdst;   // 18 x 768 fp32, contiguous
};

__global__ __launch_bounds__(256) void prep_kernel(Prep p, const uint32_t* probe) {
  const bool isbf = probe_bf(probe);
  const int z = blockIdx.z;
  if (z < 10) {
    __shared__ float tile[32][33];
    const int tx = threadIdx.x & 31, ty = threadIdx.x >> 5;
    const int x0 = blockIdx.x * 32, y0 = blockIdx.y * 32;
    const void* src = p.wsrc[z];
    ushort* dst = p.wdst[z];
#pragma unroll
    for (int i = 0; i < 4; i++) {
      const int y = y0 + ty + i * 8;
      float v;
      if (isbf) v = bf2f(((const ushort*)src)[(size_t)y * 768 + x0 + tx]);
      else      v = ((const float*)src)[(size_t)y * 768 + x0 + tx];
      tile[ty + i * 8][tx] = v;
    }
    __syncthreads();
#pragma unroll
    for (int i = 0; i < 4; i++) {
      const int row = x0 + ty + i * 8;   // n
      const int col = y0 + tx;           // k
      dst[(size_t)row * 768 + col] = f2bf(tile[tx][ty + i * 8]);
    }
  } else {
    const int idx = (blockIdx.y * 24 + blockIdx.x) * 256 + threadIdx.x;
    if (idx < 18 * 768) {
      const int e = idx / 768, i = idx - e * 768;
      float v;
      if (isbf) v = bf2f(((const ushort*)p.vsrc[e])[i]);
      else      v = ((const float*)p.vsrc[e])[i];
      p.vdst[idx] = v;
    }
  }
}

// ---------------------------------------------------------------------------
// add+LN, wave-per-row: 4 rows/block (1 wave each), no LDS, no barriers.
// ---------------------------------------------------------------------------
struct LNJob {
  const void* a; const void* b;
  const float* g; const float* be;
  float* sum_out; ushort* ln_out;
  int nrows; int abf;
};

__global__ __launch_bounds__(256) void add_ln_wave(LNJob J0, LNJob J1, const uint32_t* probe) {
  const int w = threadIdx.x >> 6, lane = threadIdx.x & 63;
  int row = blockIdx.x * 4 + w;
  LNJob j = (row < J0.nrows) ? J0 : J1;
  if (row >= J0.nrows) row -= J0.nrows;
  if (row >= j.nrows) return;
  const size_t base = (size_t)row * D_MODEL;
  const bool isbf = j.abf && probe_bf(probe);
  float x[12];
#pragma unroll
  for (int k = 0; k < 3; k++) {
    const int c = k * 256 + lane * 4;
    if (isbf) {
      const uint2 ua = *(const uint2*)((const ushort*)j.a + base + c);
      const uint2 ub = *(const uint2*)((const ushort*)j.b + base + c);
      const ushort* pa = (const ushort*)&ua;
      const ushort* pb = (const ushort*)&ub;
#pragma unroll
      for (int t = 0; t < 4; t++) x[k * 4 + t] = bf2f(pa[t]) + bf2f(pb[t]);
    } else {
      const float4 fa = *(const float4*)((const float*)j.a + base + c);
      const float4 fb = *(const float4*)((const float*)j.b + base + c);
      x[k * 4 + 0] = fa.x + fb.x; x[k * 4 + 1] = fa.y + fb.y;
      x[k * 4 + 2] = fa.z + fb.z; x[k * 4 + 3] = fa.w + fb.w;
    }
    if (j.sum_out) {
      float4 s4;
      s4.x = x[k * 4 + 0]; s4.y = x[k * 4 + 1];
      s4.z = x[k * 4 + 2]; s4.w = x[k * 4 + 3];
      *(float4*)&j.sum_out[base + c] = s4;
    }
  }
  float s = 0.f, q = 0.f;
#pragma unroll
  for (int t = 0; t < 12; t++) { s += x[t]; q += x[t] * x[t]; }
#pragma unroll
  for (int o = 32; o > 0; o >>= 1) { s += __shfl_xor(s, o); q += __shfl_xor(q, o); }
  const float mu  = s * (1.0f / D_MODEL);
  const float var = q * (1.0f / D_MODEL) - mu * mu;
  const float inv = rsqrtf(var + 1e-5f);
#pragma unroll
  for (int k = 0; k < 3; k++) {
    const int c = k * 256 + lane * 4;
    const float4 gv = *(const float4*)&j.g[c];
    const float4 bv = *(const float4*)&j.be[c];
    uint2 ou;
    ushort* oe = (ushort*)&ou;
    oe[0] = f2bf((x[k * 4 + 0] - mu) * inv * gv.x + bv.x);
    oe[1] = f2bf((x[k * 4 + 1] - mu) * inv * gv.y + bv.y);
    oe[2] = f2bf((x[k * 4 + 2] - mu) * inv * gv.z + bv.z);
    oe[3] = f2bf((x[k * 4 + 3] - mu) * inv * gv.w + bv.w);
    *(uint2*)(j.ln_out + base + c) = ou;
  }
}

// ---------------------------------------------------------------------------
// Shared 128x128 BK=64 4-fat-phase engine (R6-verified, single barrier).
// Used by gemm_mega128 only (needs 64 KiB -> 2 blocks/CU for its 2112 blocks).
// ---------------------------------------------------------------------------
#define BAR   __builtin_amdgcn_s_barrier()
#define LGKM0 do { asm volatile("s_waitcnt lgkmcnt(0)" ::: "memory"); \
                   __builtin_amdgcn_sched_barrier(0); } while (0)
#define VMC4  do { asm volatile("s_waitcnt vmcnt(4)" ::: "memory"); \
                   __builtin_amdgcn_sched_barrier(0); } while (0)
#define VMC8  do { asm volatile("s_waitcnt vmcnt(8)" ::: "memory"); \
                   __builtin_amdgcn_sched_barrier(0); } while (0)

#define RD_A(SL) do { \
  const ushort* _b = &lds[SL][0][0]; \
  _Pragma("unroll") for (int _m = 0; _m < 4; ++_m) \
  _Pragma("unroll") for (int _k = 0; _k < 2; ++_k) \
    aF[_m][_k] = *(const frag_ab*)(_b + ((wr << 6) + _m * 16 + ml) * 64 + \
                                   (((_k << 5) + (kq << 3)) ^ swz)); \
} while (0)

#define RD_B(DST, SL, no) do { \
  const ushort* _b = &lds[SL][1][0]; \
  _Pragma("unroll") for (int _n = 0; _n < 2; ++_n) \
  _Pragma("unroll") for (int _k = 0; _k < 2; ++_k) \
    DST[_n][_k] = *(const frag_ab*)(_b + ((wc << 6) + (no) + _n * 16 + ml) * 64 + \
                                    (((_k << 5) + (kq << 3)) ^ swz)); \
} while (0)

#define MM(NB, BF) do { \
  __builtin_amdgcn_s_setprio(1); \
  _Pragma("unroll") for (int _m = 0; _m < 4; ++_m) \
  _Pragma("unroll") for (int _n = 0; _n < 2; ++_n) \
  _Pragma("unroll") for (int _k = 0; _k < 2; ++_k) \
    acc[_m][(NB) + _n] = __builtin_amdgcn_mfma_f32_16x16x32_bf16( \
        aF[_m][_k], BF[_n][_k], acc[_m][(NB) + _n], 0, 0, 0); \
  __builtin_amdgcn_s_setprio(0); \
} while (0)

#define STAGE(SL, RG, PTR, RBASE, KT) do { \
  const ushort* _p = (PTR) + (size_t)((RBASE) + srow) * 768 + ((KT) << 6) + scol; \
  _Pragma("unroll") for (int _j = 0; _j < 4; ++_j) \
    __builtin_amdgcn_global_load_lds( \
        (const GLOBAL_AS void*)(_p + (size_t)(_j * 32) * 768), \
        (LDS_AS void*)((LDS_AS ushort*)&lds[SL][RG][0] + (((_j << 2) + w) << 9)), \
        16, 0, 0); \
} while (0)

#define ENGINE128() do { \
  STAGE(0, 0, jA, m0, 0); \
  STAGE(0, 1, jB, n0, 0); \
  STAGE(1, 0, jA, m0, 1); \
  VMC4; BAR; \
  for (int it = 0; it < 6; ++it) { \
    const int t1  = 2 * it + 1; \
    const int tn0 = (2 * it + 2 < 12) ? 2 * it + 2 : 11; \
    const int tn1 = (2 * it + 3 < 12) ? 2 * it + 3 : 11; \
    RD_A(0); RD_B(bF0, 0, 0); \
    STAGE(1, 1, jB, n0, t1); \
    LGKM0; \
    MM(0, bF0); \
    BAR; \
    RD_B(bF1, 0, 32); \
    STAGE(0, 0, jA, m0, tn0); \
    LGKM0; \
    MM(2, bF1); \
    VMC4; BAR; \
    RD_A(1); RD_B(bF0, 1, 0); \
    STAGE(0, 1, jB, n0, tn0); \
    LGKM0; \
    MM(0, bF0); \
    BAR; \
    RD_B(bF1, 1, 32); \
    STAGE(1, 0, jA, m0, tn1); \
    LGKM0; \
    MM(2, bF1); \
    VMC4; BAR; \
  } \
} while (0)

// ---------------------------------------------------------------------------
// Mega GEMM (verified): engine + o0/o1/vT routing epilogue.
// ---------------------------------------------------------------------------
struct GJob {
  const ushort* A; const ushort* Bt; const float* bias;
  ushort* o0; ushort* o1; ushort* vT;
  int X; int vsub; int shift;
};

__global__ __launch_bounds__(256, 2) void gemm_mega128(GJob J0, GJob J1, int n0blocks) {
  __shared__ __align__(16) ushort lds[2][2][8192];   // 64 KiB -> 2 blocks/CU
  int bid = blockIdx.x;
  GJob j = (bid < n0blocks) ? J0 : J1;
  if (bid >= n0blocks) bid -= n0blocks;
  const int tid  = threadIdx.x;
  const int lane = tid & 63, w = tid >> 6;
  const int wr = w >> 1, wc = w & 1;
  const int ml = lane & 15, kq = lane >> 4;
  const int rest = bid >> 3;
  const int x = rest % j.X, y = (bid & 7) + 8 * (rest / j.X);
  const int m0 = y << 7, n0 = x << 7;
  const int srow = (w << 3) + (lane >> 3);
  const int scol = (((lane & 7) ^ (lane >> 3)) << 3);
  const int swz  = (ml & 7) << 3;
  const ushort* jA = j.A;
  const ushort* jB = j.Bt;

  frag_cd acc[4][4] = {};
  frag_ab aF[4][2], bF0[2][2], bF1[2][2];

  ENGINE128();

  const int sub  = x / 6;                  // 768/128 = 6 tiles per sub-block
  const int mask = (1 << j.shift) - 1;
#pragma unroll
  for (int mt = 0; mt < 4; mt++) {
#pragma unroll
    for (int nt = 0; nt < 4; nt++) {
      const int row0 = m0 + wr * 64 + mt * 16 + kq * 4;
      const int col  = n0 + wc * 64 + nt * 16 + ml;
      const float bc = j.bias[col];
      if (sub == j.vsub) {
        const int hcol = col - sub * 768;
        const int hh = hcol >> 6, dd = hcol & 63;
        const int bb = row0 >> j.shift;
        const int jj = row0 & mask;
        uint2 pack;
        ushort* pe = (ushort*)&pack;
#pragma unroll
        for (int r = 0; r < 4; r++) pe[r] = f2bf(acc[mt][nt][r] + bc);
        *(uint2*)(j.vT + ((((size_t)(bb * HEADS + hh) << 6) + dd) << j.shift) + jj) = pack;
      } else {
        ushort* out = (sub == 0) ? j.o0 : j.o1;
        const int cl = col - sub * 768;
#pragma unroll
        for (int r = 0; r < 4; r++)
          out[(size_t)(row0 + r) * 768 + cl] = f2bf(acc[mt][nt][r] + bc);
      }
    }
  }
}

#undef RD_A
#undef RD_B
#undef MM
#undef STAGE
#undef ENGINE128

// ---------------------------------------------------------------------------
// gemm_v3d: deep-pipelined 128x128 BK=64 for the 192-block projections.
// 4-slot / 3-tile-lookahead pipeline, 8 waves, 128 KiB LDS (1 block/CU —
// free at 192 blocks). R8 FIX: prologue VMC8+BAR (cross-wave base case:
// vmcnt is per-wave; without a barrier after the prologue, wave A read
// slot-0 rows staged by wave B before B issued its loads -> R7 absmax fail).
//
// Ledger (4 loads/thread/tile): prologue stages tiles 0-2 (12 outstanding);
// VMC8 retires tile 0; BAR -> tile 0 collectively landed. Phase t: STAGE
// tile t+3 (8->12), VMC8 retires tile t+1 (issued phase t-2 -> 2-phase
// lookahead); VMC8 precedes end-of-phase BAR, so after BAR(t) all waves'
// tile-(t+1) loads landed -> phase t+1 reads safe. Overwrite: slot (t+3)&3
// last read phase t-1, reads done at LGKM0(t-1) < BAR(t-1) < STAGE(t).
// Never vmcnt(0) in loop. Tail clamps to tile 11 into dead slots.
// ---------------------------------------------------------------------------
#define DRD_A(SL) do { \
  const ushort* _b = &lds[SL][0][0]; \
  _Pragma("unroll") for (int _m = 0; _m < 4; ++_m) \
  _Pragma("unroll") for (int _k = 0; _k < 2; ++_k) \
    aF[_m][_k] = *(const frag_ab*)(_b + ((wr << 6) + _m * 16 + ml) * 64 + \
                                   (((_k << 5) + (kq << 3)) ^ swz)); \
} while (0)

#define DRD_B(SL) do { \
  const ushort* _b = &lds[SL][1][0]; \
  _Pragma("unroll") for (int _n = 0; _n < 2; ++_n) \
  _Pragma("unroll") for (int _k = 0; _k < 2; ++_k) \
    bF[_n][_k] = *(const frag_ab*)(_b + ((wc << 5) + _n * 16 + ml) * 64 + \
                                   (((_k << 5) + (kq << 3)) ^ swz)); \
} while (0)

#define DMM() do { \
  __builtin_amdgcn_s_setprio(1); \
  _Pragma("unroll") for (int _m = 0; _m < 4; ++_m) \
  _Pragma("unroll") for (int _n = 0; _n < 2; ++_n) \
  _Pragma("unroll") for (int _k = 0; _k < 2; ++_k) \
    acc[_m][_n] = __builtin_amdgcn_mfma_f32_16x16x32_bf16( \
        aF[_m][_k], bF[_n][_k], acc[_m][_n], 0, 0, 0); \
  __builtin_amdgcn_s_setprio(0); \
} while (0)

// stage one 16KB region (A or B) of tile KT into slot SL: 2 loads/thread.
#define DSTG(SL, RG, PTR, RBASE, KT) do { \
  const ushort* _p = (PTR) + (size_t)((RBASE) + srow) * 768 + ((KT) << 6) + scol; \
  __builtin_amdgcn_global_load_lds((const GLOBAL_AS void*)_p, \
      (LDS_AS void*)((LDS_AS ushort*)&lds[SL][RG][0] + (w << 9)), 16, 0, 0); \
  __builtin_amdgcn_global_load_lds((const GLOBAL_AS void*)(_p + (size_t)64 * 768), \
      (LDS_AS void*)((LDS_AS ushort*)&lds[SL][RG][0] + ((8 + w) << 9)), 16, 0, 0); \
} while (0)

__global__ __launch_bounds__(512, 1) void gemm_v3d(
    const ushort* __restrict__ A, const ushort* __restrict__ Bt,
    const float* __restrict__ bias,
    const void* __restrict__ resid, int rmode,
    void* __restrict__ C, int relu, int omode,
    const uint32_t* __restrict__ probe, int X) {
  __shared__ __align__(16) ushort lds[4][2][8192];   // 128 KiB
  const int bid  = blockIdx.x;
  const int tid  = threadIdx.x;
  const int lane = tid & 63, w = tid >> 6;            // w in 0..7
  const int wr = w >> 2, wc = w & 3;                  // 2M x 4N waves
  const int ml = lane & 15, kq = lane >> 4;
  const int rest = bid >> 3;
  const int x = rest % X, y = (bid & 7) + 8 * (rest / X);
  const int m0 = y << 7, n0 = x << 7;
  // staging rows: thread covers region rows {srow, srow+64}; (row&7) equal
  // for both, so one pre-swizzled source column works.
  const int srow = (w << 3) + (lane >> 3);            // 0..63
  const int scol = (((lane & 7) ^ (lane >> 3)) << 3);
  const int swz  = (ml & 7) << 3;

  frag_cd acc[4][2] = {};
  frag_ab aF[4][2], bF[2][2];

  // prologue: tiles 0,1,2 -> slots 0,1,2 (12 loads/thread outstanding),
  // then VMC8 (tile 0 landed) + BAR (cross-wave base case — the R7 fix).
  DSTG(0, 0, A, m0, 0); DSTG(0, 1, Bt, n0, 0);
  DSTG(1, 0, A, m0, 1); DSTG(1, 1, Bt, n0, 1);
  DSTG(2, 0, A, m0, 2); DSTG(2, 1, Bt, n0, 2);
  VMC8; BAR;

#pragma unroll 4
  for (int t = 0; t < 12; ++t) {
    const int sl  = t & 3;
    const int tn  = (t + 3 < 12) ? t + 3 : 11;   // clamped prefetch
    const int sln = (t + 3) & 3;
    DSTG(sln, 0, A, m0, tn); DSTG(sln, 1, Bt, n0, tn);
    VMC8;                       // tiles <= t+1 landed (per-wave)
    DRD_A(sl); DRD_B(sl);
    LGKM0;
    DMM();
    BAR;                        // publishes tile t+1 cross-wave; frees slot
  }

  const bool obf = (omode == 1) || (omode == 2 && probe_bf(probe));
  const bool rbf = (rmode == 2) && probe_bf(probe);
#pragma unroll
  for (int mt = 0; mt < 4; mt++) {
#pragma unroll
    for (int nt = 0; nt < 2; nt++) {
      const int row0 = m0 + wr * 64 + mt * 16 + kq * 4;
      const int col  = n0 + wc * 32 + nt * 16 + ml;
      const float bc = bias[col];
#pragma unroll
      for (int r = 0; r < 4; r++) {
        const size_t off = (size_t)(row0 + r) * 768 + col;
        float v = acc[mt][nt][r] + bc;
        if (rmode != 0)
          v += rbf ? bf2f(((const ushort*)resid)[off]) : ((const float*)resid)[off];
        if (relu) v = fmaxf(v, 0.f);
        if (obf) ((ushort*)C)[off] = f2bf(v);
        else     ((float*)C)[off]  = v;
      }
    }
  }
}

#undef DRD_A
#undef DRD_B
#undef DMM
#undef DSTG

// ---------------------------------------------------------------------------
// MFMA flash attention (R4-verified): double-buffered K/V LDS -> ONE barrier
// per KV-tile, + T14 reg prefetch. LDS 52 KB -> 3 blocks/CU.
// ---------------------------------------------------------------------------
#define FS 68
__global__ __launch_bounds__(256) void fattn_mfma(
    const ushort* __restrict__ Q, const ushort* __restrict__ Kp,
    const ushort* __restrict__ vT, ushort* __restrict__ O, int Skv) {
  __shared__ __align__(16) ushort Qs[64 * FS];
  __shared__ __align__(16) ushort Ks[2][64 * FS];
  __shared__ __align__(16) ushort Vt[2][64 * FS];
  __shared__ __align__(16) ushort Ps[64 * FS];
  const int tid  = threadIdx.x;
  const int lane = tid & 63, w = tid >> 6;
  const int ml   = lane & 15, kq = lane >> 4;
  const int bid = blockIdx.x;
  const int g8  = bid & 7;
  const int qt  = (bid >> 3) & 3;
  const int g   = (bid >> 5) * 8 + g8;      // 0..191 = b*12+h
  const int h   = g % HEADS;
  const int b   = g / HEADS;
  const int q0  = qt * 64;
  const ushort* Qb  = Q  + ((size_t)b * SP + q0) * D_MODEL + h * D_HEAD;
  const ushort* Kb  = Kp + (size_t)b * Skv * D_MODEL + h * D_HEAD;
  const ushort* vTb = vT + (size_t)g * 64 * Skv;

  const int r0 = tid >> 3, p0 = tid & 7;
  const int r1 = r0 + 32;

  for (int c = tid; c < 512; c += 256) {
    const int r = c >> 3, p = c & 7;
    *(uint4*)&Qs[r * FS + p * 8] = *(const uint4*)(Qb + (size_t)r * D_MODEL + p * 8);
  }

  uint4 kr0 = *(const uint4*)(Kb + (size_t)r0 * D_MODEL + p0 * 8);
  uint4 vr0 = *(const uint4*)(vTb + (size_t)r0 * Skv + p0 * 8);
  uint4 kr1 = *(const uint4*)(Kb + (size_t)r1 * D_MODEL + p0 * 8);
  uint4 vr1 = *(const uint4*)(vTb + (size_t)r1 * Skv + p0 * 8);
  *(uint4*)&Ks[0][r0 * FS + p0 * 8] = kr0;
  *(uint4*)&Vt[0][r0 * FS + p0 * 8] = vr0;
  *(uint4*)&Ks[0][r1 * FS + p0 * 8] = kr1;
  *(uint4*)&Vt[0][r1 * FS + p0 * 8] = vr1;
  __syncthreads();

  frag_ab qa[2];
#pragma unroll
  for (int kc = 0; kc < 2; kc++)
    qa[kc] = *(const frag_ab*)&Qs[(w * 16 + ml) * FS + kc * 32 + kq * 8];

  frag_cd oc[4] = {};
  float m_i[4], l_i[4];
#pragma unroll
  for (int r = 0; r < 4; r++) { m_i[r] = -1e30f; l_i[r] = 0.f; }
  const float SCL = 0.125f * 1.44269504f;
  const int NT = Skv >> 6;

  for (int t = 0; t < NT; ++t) {
    const int cb = t & 1;
    if (t + 1 < NT) {                      // T14: next tile -> regs early
      const int jn = (t + 1) << 6;
      kr0 = *(const uint4*)(Kb + (size_t)(jn + r0) * D_MODEL + p0 * 8);
      vr0 = *(const uint4*)(vTb + (size_t)r0 * Skv + jn + p0 * 8);
      kr1 = *(const uint4*)(Kb + (size_t)(jn + r1) * D_MODEL + p0 * 8);
      vr1 = *(const uint4*)(vTb + (size_t)r1 * Skv + jn + p0 * 8);
    }

    frag_cd sc[4] = {};
#pragma unroll
    for (int nt = 0; nt < 4; nt++)
#pragma unroll
      for (int kc = 0; kc < 2; kc++) {
        const frag_ab bfr = *(const frag_ab*)&Ks[cb][(nt * 16 + ml) * FS + kc * 32 + kq * 8];
        sc[nt] = __builtin_amdgcn_mfma_f32_16x16x32_bf16(qa[kc], bfr, sc[nt], 0, 0, 0);
      }
#pragma unroll
    for (int nt = 0; nt < 4; nt++)
#pragma unroll
      for (int r = 0; r < 4; r++) sc[nt][r] *= SCL;

    float al[4];
#pragma unroll
    for (int r = 0; r < 4; r++) {
      float mx = fmaxf(fmaxf(sc[0][r], sc[1][r]), fmaxf(sc[2][r], sc[3][r]));
#pragma unroll
      for (int m = 1; m < 16; m <<= 1) mx = fmaxf(mx, __shfl_xor(mx, m, 16));
      const float mnew = fmaxf(m_i[r], mx);
      al[r] = exp2f(m_i[r] - mnew);
      float p[4], s = 0.f;
#pragma unroll
      for (int nt = 0; nt < 4; nt++) { p[nt] = exp2f(sc[nt][r] - mnew); s += p[nt]; }
#pragma unroll
      for (int m = 1; m < 16; m <<= 1) s += __shfl_xor(s, m, 16);
      l_i[r] = l_i[r] * al[r] + s;
      m_i[r] = mnew;
      const int prow = (w * 16 + kq * 4 + r) * FS;
#pragma unroll
      for (int nt = 0; nt < 4; nt++) Ps[prow + nt * 16 + ml] = f2bf(p[nt]);
    }
#pragma unroll
    for (int dt = 0; dt < 4; dt++)
#pragma unroll
      for (int r = 0; r < 4; r++) oc[dt][r] *= al[r];

#pragma unroll
    for (int kc = 0; kc < 2; kc++) {
      const frag_ab pa = *(const frag_ab*)&Ps[(w * 16 + ml) * FS + kc * 32 + kq * 8];
#pragma unroll
      for (int dt = 0; dt < 4; dt++) {
        const frag_ab vb = *(const frag_ab*)&Vt[cb][(dt * 16 + ml) * FS + kc * 32 + kq * 8];
        oc[dt] = __builtin_amdgcn_mfma_f32_16x16x32_bf16(pa, vb, oc[dt], 0, 0, 0);
      }
    }

    if (t + 1 < NT) {
      *(uint4*)&Ks[cb ^ 1][r0 * FS + p0 * 8] = kr0;
      *(uint4*)&Vt[cb ^ 1][r0 * FS + p0 * 8] = vr0;
      *(uint4*)&Ks[cb ^ 1][r1 * FS + p0 * 8] = kr1;
      *(uint4*)&Vt[cb ^ 1][r1 * FS + p0 * 8] = vr1;
      __syncthreads();
    }
  }

  float inv[4];
#pragma unroll
  for (int r = 0; r < 4; r++) inv[r] = 1.0f / l_i[r];
#pragma unroll
  for (int dt = 0; dt < 4; dt++)
#pragma unroll
    for (int r = 0; r < 4; r++)
      O[((size_t)b * SP + q0 + w * 16 + kq * 4 + r) * D_MODEL + h * D_HEAD + dt * 16 + ml] =
          f2bf(oc[dt][r] * inv[r]);
}

// ---------------------------------------------------------------------------
extern "C" void kernel_launch(void* const* d_in, const int* in_sizes, int n_in,
                              void* d_out, int out_size, void* d_ws, size_t ws_size,
                              hipStream_t stream) {
  (void)in_sizes; (void)n_in; (void)out_size;
  char* base = (char*)d_ws;
  size_t off = 256;
  auto alloc = [&](size_t bytes) -> char* {
    char* p = base + off;
    off = (off + bytes + 255) & ~(size_t)255;
    return p;
  };
  const size_t WB = (size_t)768 * 768 * 2;
  ushort* Wt[10];
  for (int i = 0; i < 10; i++) Wt[i] = (ushort*)alloc(WB);   // contiguous
  float* vecs = (float*)alloc(18 * 768 * 4);                 // 10 bias + 8 ln
  float* biasF[10];
  for (int i = 0; i < 10; i++) biasF[i] = vecs + i * 768;
  float* lnF = vecs + 10 * 768;
  float* prompt0 = (float*)alloc((size_t)NP * 768 * 4);
  float* cur     = (float*)alloc((size_t)NP * 768 * 4);
  ushort* q_bf   = (ushort*)alloc((size_t)NP * 768 * 2);
  ushort* k_s    = (ushort*)alloc((size_t)NP * 768 * 2);
  ushort* k_c    = (ushort*)alloc((size_t)NI * 768 * 2);
  ushort* xln_bf = (ushort*)alloc((size_t)NP * 768 * 2);
  ushort* xi_bf  = (ushort*)alloc((size_t)NI * 768 * 2);
  ushort* obuf_bf = (ushort*)alloc((size_t)NP * 768 * 2);
  ushort* ffn1_bf = (ushort*)alloc((size_t)NP * 768 * 2);
  ushort* vT_s   = (ushort*)alloc((size_t)BATCH * HEADS * 64 * SP * 2);
  ushort* vT_c   = (ushort*)alloc((size_t)BATCH * HEADS * 64 * SI * 2);
  if (ws_size < off) return;

  const uint32_t* probe = (const uint32_t*)d_in[4];   // ln_p1_g
  const int widx[10] = {12, 14, 16, 18, 20, 22, 24, 26, 28, 30};
  const int bidx[10] = {13, 15, 17, 19, 21, 23, 25, 27, 29, 31};

  // 1. prep: weight transpose + param convert
  Prep pr{};
  for (int i = 0; i < 10; i++) { pr.wsrc[i] = d_in[widx[i]]; pr.wdst[i] = Wt[i]; }
  for (int i = 0; i < 10; i++) pr.vsrc[i] = d_in[bidx[i]];
  for (int i = 0; i < 8;  i++) pr.vsrc[10 + i] = d_in[4 + i];
  pr.vdst = vecs;
  prep_kernel<<<dim3(24, 24, 11), 256, 0, stream>>>(pr, probe);

  float* G1 = lnF + 0 * 768, *B1 = lnF + 1 * 768;   // ln_p1
  float* G2 = lnF + 2 * 768, *B2 = lnF + 3 * 768;   // ln_p2
  float* G3 = lnF + 4 * 768, *B3 = lnF + 5 * 768;   // ln_p3
  float* Gi = lnF + 6 * 768, *Bi = lnF + 7 * 768;   // ln_i1

  // 2. LN1(prompt+posp, sum->prompt0) + LNi(image+posi) merged, wave-per-row
  LNJob L0{d_in[1], d_in[3], G1, B1, prompt0, xln_bf, NP, 1};
  LNJob Li{d_in[0], d_in[2], Gi, Bi, nullptr, xi_bf,  NI, 1};
  add_ln_wave<<<(NP + NI) / 4, 256, 0, stream>>>(L0, Li, probe);

  // 3. mega GEMM (128x128, 2 blocks/CU): self QKV (576) + cross KV (1536).
  GJob js{xln_bf, Wt[0], biasF[0], q_bf, k_s, vT_s, 18, 2, 8};
  GJob jc{xi_bf,  Wt[5], biasF[5], k_c,  nullptr, vT_c, 12, 1, 10};
  gemm_mega128<<<576 + 1536, 256, 0, stream>>>(js, jc, 576);

  // 4. self flash attention
  fattn_mfma<<<BATCH * HEADS * (SP / 64), 256, 0, stream>>>(q_bf, k_s, vT_s, obuf_bf, SP);

  // 5. O-proj self: cur(fp32) = obuf@Wo + bo + prompt(input dtype)
  gemm_v3d<<<192, 512, 0, stream>>>(obuf_bf, Wt[3], biasF[3],
      d_in[1], 2, cur, 0, 0, probe, 6);

  // 6. LN2(cur + prompt0)
  LNJob L2{cur, prompt0, G2, B2, nullptr, xln_bf, NP, 0};
  LNJob Lz{}; Lz.nrows = 0;
  add_ln_wave<<<NP / 4, 256, 0, stream>>>(L2, Lz, probe);

  // 7. cross Q projection (bf16 out)
  gemm_v3d<<<192, 512, 0, stream>>>(xln_bf, Wt[4], biasF[4],
      nullptr, 0, q_bf, 0, 1, probe, 6);

  // 8. cross flash attention
  fattn_mfma<<<BATCH * HEADS * (SP / 64), 256, 0, stream>>>(q_bf, k_c, vT_c, obuf_bf, SI);

  // 9. O-proj cross: cur = obuf@Wo2 + bo2 + cur (fp32, in-place per-element)
  gemm_v3d<<<192, 512, 0, stream>>>(obuf_bf, Wt[7], biasF[7],
      cur, 1, cur, 0, 0, probe, 6);

  // 10. LN3(cur + prompt0)
  LNJob L3{cur, prompt0, G3, B3, nullptr, xln_bf, NP, 0};
  add_ln_wave<<<NP / 4, 256, 0, stream>>>(L3, Lz, probe);

  // 11. FFN1: relu(xln@W1+b1) -> bf16
  gemm_v3d<<<192, 512, 0, stream>>>(xln_bf, Wt[8], biasF[8],
      nullptr, 0, ffn1_bf, 1, 1, probe, 6);

  // 12. FFN2: d_out (dtype per probe)
  gemm_v3d<<<192, 512, 0, stream>>>(ffn1_bf, Wt[9], biasF[9],
      nullptr, 0, d_out, 0, 2, probe, 6);
}

// Round 9
// 464.435 us; speedup vs baseline: 1.0854x; 1.0069x over previous
//
#include <hip/hip_runtime.h>
#include <hip/hip_bf16.h>
#include <stdint.h>
#include <math.h>

#define D_MODEL 768
#define HEADS 12
#define D_HEAD 64
#define BATCH 16
#define SP 256
#define SI 1024
#define NP (BATCH * SP)   // 4096 prompt rows
#define NI (BATCH * SI)   // 16384 image rows

#define GLOBAL_AS __attribute__((address_space(1)))
#define LDS_AS    __attribute__((address_space(3)))

typedef __attribute__((ext_vector_type(8))) short  frag_ab;  // 8 bf16 (4 VGPRs)
typedef __attribute__((ext_vector_type(4))) float  frag_cd;  // 4 fp32 acc

static __device__ __forceinline__ ushort f2bf(float f) {
  __hip_bfloat16 h = __float2bfloat16(f);
  return *(ushort*)&h;
}
static __device__ __forceinline__ float bf2f(ushort u) {
  return __bfloat162float(*(__hip_bfloat16*)&u);
}
// dtype hedge (round-1 verified: bf16). ln_p1_g all-ones word0 probe.
static __device__ __forceinline__ bool probe_bf(const uint32_t* p) {
  return p[0] == 0x3F803F80u;
}

// ---------------------------------------------------------------------------
// prep: z<10 -> weight transpose [k][n]->[n][k] bf16 ; z==10 -> convert the
// 18 param vectors (10 biases + 8 LN g/b) to fp32 (contiguous dst).
// ---------------------------------------------------------------------------
struct Prep {
  const void* wsrc[10]; ushort* wdst[10];
  const void* vsrc[18]; float* vdst;   // 18 x 768 fp32, contiguous
};

__global__ __launch_bounds__(256) void prep_kernel(Prep p, const uint32_t* probe) {
  const bool isbf = probe_bf(probe);
  const int z = blockIdx.z;
  if (z < 10) {
    __shared__ float tile[32][33];
    const int tx = threadIdx.x & 31, ty = threadIdx.x >> 5;
    const int x0 = blockIdx.x * 32, y0 = blockIdx.y * 32;
    const void* src = p.wsrc[z];
    ushort* dst = p.wdst[z];
#pragma unroll
    for (int i = 0; i < 4; i++) {
      const int y = y0 + ty + i * 8;
      float v;
      if (isbf) v = bf2f(((const ushort*)src)[(size_t)y * 768 + x0 + tx]);
      else      v = ((const float*)src)[(size_t)y * 768 + x0 + tx];
      tile[ty + i * 8][tx] = v;
    }
    __syncthreads();
#pragma unroll
    for (int i = 0; i < 4; i++) {
      const int row = x0 + ty + i * 8;   // n
      const int col = y0 + tx;           // k
      dst[(size_t)row * 768 + col] = f2bf(tile[tx][ty + i * 8]);
    }
  } else {
    const int idx = (blockIdx.y * 24 + blockIdx.x) * 256 + threadIdx.x;
    if (idx < 18 * 768) {
      const int e = idx / 768, i = idx - e * 768;
      float v;
      if (isbf) v = bf2f(((const ushort*)p.vsrc[e])[i]);
      else      v = ((const float*)p.vsrc[e])[i];
      p.vdst[idx] = v;
    }
  }
}

// ---------------------------------------------------------------------------
// add+LN, wave-per-row: 4 rows/block (1 wave each), no LDS, no barriers.
// ---------------------------------------------------------------------------
struct LNJob {
  const void* a; const void* b;
  const float* g; const float* be;
  float* sum_out; ushort* ln_out;
  int nrows; int abf;
};

__global__ __launch_bounds__(256) void add_ln_wave(LNJob J0, LNJob J1, const uint32_t* probe) {
  const int w = threadIdx.x >> 6, lane = threadIdx.x & 63;
  int row = blockIdx.x * 4 + w;
  LNJob j = (row < J0.nrows) ? J0 : J1;
  if (row >= J0.nrows) row -= J0.nrows;
  if (row >= j.nrows) return;
  const size_t base = (size_t)row * D_MODEL;
  const bool isbf = j.abf && probe_bf(probe);
  float x[12];
#pragma unroll
  for (int k = 0; k < 3; k++) {
    const int c = k * 256 + lane * 4;
    if (isbf) {
      const uint2 ua = *(const uint2*)((const ushort*)j.a + base + c);
      const uint2 ub = *(const uint2*)((const ushort*)j.b + base + c);
      const ushort* pa = (const ushort*)&ua;
      const ushort* pb = (const ushort*)&ub;
#pragma unroll
      for (int t = 0; t < 4; t++) x[k * 4 + t] = bf2f(pa[t]) + bf2f(pb[t]);
    } else {
      const float4 fa = *(const float4*)((const float*)j.a + base + c);
      const float4 fb = *(const float4*)((const float*)j.b + base + c);
      x[k * 4 + 0] = fa.x + fb.x; x[k * 4 + 1] = fa.y + fb.y;
      x[k * 4 + 2] = fa.z + fb.z; x[k * 4 + 3] = fa.w + fb.w;
    }
    if (j.sum_out) {
      float4 s4;
      s4.x = x[k * 4 + 0]; s4.y = x[k * 4 + 1];
      s4.z = x[k * 4 + 2]; s4.w = x[k * 4 + 3];
      *(float4*)&j.sum_out[base + c] = s4;
    }
  }
  float s = 0.f, q = 0.f;
#pragma unroll
  for (int t = 0; t < 12; t++) { s += x[t]; q += x[t] * x[t]; }
#pragma unroll
  for (int o = 32; o > 0; o >>= 1) { s += __shfl_xor(s, o); q += __shfl_xor(q, o); }
  const float mu  = s * (1.0f / D_MODEL);
  const float var = q * (1.0f / D_MODEL) - mu * mu;
  const float inv = rsqrtf(var + 1e-5f);
#pragma unroll
  for (int k = 0; k < 3; k++) {
    const int c = k * 256 + lane * 4;
    const float4 gv = *(const float4*)&j.g[c];
    const float4 bv = *(const float4*)&j.be[c];
    uint2 ou;
    ushort* oe = (ushort*)&ou;
    oe[0] = f2bf((x[k * 4 + 0] - mu) * inv * gv.x + bv.x);
    oe[1] = f2bf((x[k * 4 + 1] - mu) * inv * gv.y + bv.y);
    oe[2] = f2bf((x[k * 4 + 2] - mu) * inv * gv.z + bv.z);
    oe[3] = f2bf((x[k * 4 + 3] - mu) * inv * gv.w + bv.w);
    *(uint2*)(j.ln_out + base + c) = ou;
  }
}

// ---------------------------------------------------------------------------
// common waitcnt macros (rule #18: sched_barrier after inline-asm waitcnt)
// ---------------------------------------------------------------------------
#define BAR   __builtin_amdgcn_s_barrier()
#define LGKM0 do { asm volatile("s_waitcnt lgkmcnt(0)" ::: "memory"); \
                   __builtin_amdgcn_sched_barrier(0); } while (0)
#define VMC4  do { asm volatile("s_waitcnt vmcnt(4)" ::: "memory"); \
                   __builtin_amdgcn_sched_barrier(0); } while (0)
#define VMC8  do { asm volatile("s_waitcnt vmcnt(8)" ::: "memory"); \
                   __builtin_amdgcn_sched_barrier(0); } while (0)

// ---------------------------------------------------------------------------
// gemm_mega32: mega GEMM rebuilt on the R8-verified v3d deep pipeline.
// 128x128 tile, BK=32, 4 slots (tiles t..t+3 in flight), 512 thr (8 waves,
// 2Mx4N, 64x32 out each), 64 KiB LDS -> 2 blocks/CU (grid 2112 needs it).
// vs old engine: wait covers loads issued 2 phases back (was ~1) and 16
// waves/CU (was 8) — attacks the latency stall R5/R6 isolated.
//
// LDS lds[slot(4)][{A,B}(2)][128*32 bf16] = 64 KiB. Region row = 4 chunks of
// 16B. Swizzle: phys chunk = logical chunk ^ (row&3); staging pre-swizzles
// the GLOBAL source chunk (linear LDS dest, rule #21); ds_read XORs the same
// (worst 4-way bank conflict vs 8-way unswizzled).
//
// Ledger (2 loads/thread/tile): prologue stages tiles 0-2 (6 outstanding);
// VMC4 retires tile 0; BAR -> cross-wave base case (R7 lesson). Phase t:
// STAGE tile t+3 (4->6); VMC4 retires tile t+1 (issued phase t-2 -> 2-phase
// cover); VMC4 precedes end-of-phase BAR -> after BAR(t) all waves' tile
// (t+1) loads landed. Overwrite: slot (t+3)&3 last read phase t-1, done at
// LGKM0(t-1) < BAR(t-1) < STAGE(t). Tail clamps to tile 23 into dead slots.
// Never vmcnt(0) in loop.
// ---------------------------------------------------------------------------
struct GJob {
  const ushort* A; const ushort* Bt; const float* bias;
  ushort* o0; ushort* o1; ushort* vT;
  int X; int vsub; int shift;
};

#define MSTG(SL, RG, PTR, RBASE, KT) \
  __builtin_amdgcn_global_load_lds( \
      (const GLOBAL_AS void*)((PTR) + (size_t)((RBASE) + srow) * 768 + ((KT) << 5) + scol), \
      (LDS_AS void*)((LDS_AS ushort*)&lds[SL][RG][0] + (w << 9)), 16, 0, 0)

#define MRD_A(SL) do { \
  const ushort* _b = &lds[SL][0][0]; \
  _Pragma("unroll") for (int _m = 0; _m < 4; ++_m) \
    aF[_m] = *(const frag_ab*)(_b + (((wr << 6) + _m * 16 + ml) << 5) + \
                               ((kq << 3) ^ swz)); \
} while (0)

#define MRD_B(SL) do { \
  const ushort* _b = &lds[SL][1][0]; \
  _Pragma("unroll") for (int _n = 0; _n < 2; ++_n) \
    bF[_n] = *(const frag_ab*)(_b + (((wc << 5) + _n * 16 + ml) << 5) + \
                               ((kq << 3) ^ swz)); \
} while (0)

#define MMM() do { \
  __builtin_amdgcn_s_setprio(1); \
  _Pragma("unroll") for (int _m = 0; _m < 4; ++_m) \
  _Pragma("unroll") for (int _n = 0; _n < 2; ++_n) \
    acc[_m][_n] = __builtin_amdgcn_mfma_f32_16x16x32_bf16( \
        aF[_m], bF[_n], acc[_m][_n], 0, 0, 0); \
  __builtin_amdgcn_s_setprio(0); \
} while (0)

__global__ __launch_bounds__(512, 4) void gemm_mega32(GJob J0, GJob J1, int n0blocks) {
  __shared__ __align__(16) ushort lds[4][2][4096];   // 64 KiB -> 2 blocks/CU
  int bid = blockIdx.x;
  GJob j = (bid < n0blocks) ? J0 : J1;
  if (bid >= n0blocks) bid -= n0blocks;
  const int tid  = threadIdx.x;
  const int lane = tid & 63, w = tid >> 6;            // w in 0..7
  const int wr = w >> 2, wc = w & 3;                  // 2M x 4N waves
  const int ml = lane & 15, kq = lane >> 4;
  const int rest = bid >> 3;
  const int x = rest % j.X, y = (bid & 7) + 8 * (rest / j.X);
  const int m0 = y << 7, n0 = x << 7;
  // staging: thread -> region row srow = tid>>2, chunk tid&3; source chunk
  // pre-swizzled so linear LDS dest holds the swizzled layout.
  const int srow = tid >> 2;                          // 0..127
  const int scol = (((tid & 3) ^ ((tid >> 2) & 3)) << 3);   // ushorts
  const int swz  = (ml & 3) << 3;                     // ds_read XOR (ushorts)
  const ushort* jA = j.A;
  const ushort* jB = j.Bt;

  frag_cd acc[4][2] = {};
  frag_ab aF[4], bF[2];

  // prologue: tiles 0,1,2 -> slots 0,1,2; VMC4 retires tile 0; BAR = base case.
  MSTG(0, 0, jA, m0, 0); MSTG(0, 1, jB, n0, 0);
  MSTG(1, 0, jA, m0, 1); MSTG(1, 1, jB, n0, 1);
  MSTG(2, 0, jA, m0, 2); MSTG(2, 1, jB, n0, 2);
  VMC4; BAR;

#pragma unroll 4
  for (int t = 0; t < 24; ++t) {
    const int sl  = t & 3;
    const int tn  = (t + 3 < 24) ? t + 3 : 23;   // clamped prefetch
    const int sln = (t + 3) & 3;
    MSTG(sln, 0, jA, m0, tn); MSTG(sln, 1, jB, n0, tn);
    VMC4;                       // tile t+1 landed (issued 2 phases back)
    MRD_A(sl); MRD_B(sl);
    LGKM0;
    MMM();
    BAR;                        // publishes tile t+1 cross-wave; frees slot
  }

  // epilogue: routing identical to verified mega; wave geometry re-indexed
  // (8 waves, 64x32 out each: col = n0 + wc*32 + nt*16 + ml, nt in 0..1).
  const int sub  = x / 6;                  // 768/128 = 6 tiles per sub-block
  const int mask = (1 << j.shift) - 1;
#pragma unroll
  for (int mt = 0; mt < 4; mt++) {
#pragma unroll
    for (int nt = 0; nt < 2; nt++) {
      const int row0 = m0 + (wr << 6) + mt * 16 + kq * 4;
      const int col  = n0 + (wc << 5) + nt * 16 + ml;
      const float bc = j.bias[col];
      if (sub == j.vsub) {
        const int hcol = col - sub * 768;
        const int hh = hcol >> 6, dd = hcol & 63;
        const int bb = row0 >> j.shift;
        const int jj = row0 & mask;
        uint2 pack;
        ushort* pe = (ushort*)&pack;
#pragma unroll
        for (int r = 0; r < 4; r++) pe[r] = f2bf(acc[mt][nt][r] + bc);
        *(uint2*)(j.vT + ((((size_t)(bb * HEADS + hh) << 6) + dd) << j.shift) + jj) = pack;
      } else {
        ushort* out = (sub == 0) ? j.o0 : j.o1;
        const int cl = col - sub * 768;
#pragma unroll
        for (int r = 0; r < 4; r++)
          out[(size_t)(row0 + r) * 768 + cl] = f2bf(acc[mt][nt][r] + bc);
      }
    }
  }
}

#undef MSTG
#undef MRD_A
#undef MRD_B
#undef MMM

// ---------------------------------------------------------------------------
// gemm_v3d (R8-verified): deep-pipelined 128x128 BK=64 for the 192-block
// projections. 4-slot / 3-tile-lookahead, 8 waves, 128 KiB LDS (1 block/CU).
// Ledger: prologue tiles 0-2 (12 outstanding), VMC8 retires tile 0, BAR =
// cross-wave base case. Phase t: STAGE t+3 (8->12), VMC8 retires tile t+1
// (2-phase cover) before end-of-phase BAR. Never vmcnt(0) in loop.
// ---------------------------------------------------------------------------
#define DRD_A(SL) do { \
  const ushort* _b = &lds[SL][0][0]; \
  _Pragma("unroll") for (int _m = 0; _m < 4; ++_m) \
  _Pragma("unroll") for (int _k = 0; _k < 2; ++_k) \
    aF[_m][_k] = *(const frag_ab*)(_b + ((wr << 6) + _m * 16 + ml) * 64 + \
                                   (((_k << 5) + (kq << 3)) ^ swz)); \
} while (0)

#define DRD_B(SL) do { \
  const ushort* _b = &lds[SL][1][0]; \
  _Pragma("unroll") for (int _n = 0; _n < 2; ++_n) \
  _Pragma("unroll") for (int _k = 0; _k < 2; ++_k) \
    bF[_n][_k] = *(const frag_ab*)(_b + ((wc << 5) + _n * 16 + ml) * 64 + \
                                   (((_k << 5) + (kq << 3)) ^ swz)); \
} while (0)

#define DMM() do { \
  __builtin_amdgcn_s_setprio(1); \
  _Pragma("unroll") for (int _m = 0; _m < 4; ++_m) \
  _Pragma("unroll") for (int _n = 0; _n < 2; ++_n) \
  _Pragma("unroll") for (int _k = 0; _k < 2; ++_k) \
    acc[_m][_n] = __builtin_amdgcn_mfma_f32_16x16x32_bf16( \
        aF[_m][_k], bF[_n][_k], acc[_m][_n], 0, 0, 0); \
  __builtin_amdgcn_s_setprio(0); \
} while (0)

// stage one 16KB region (A or B) of tile KT into slot SL: 2 loads/thread.
#define DSTG(SL, RG, PTR, RBASE, KT) do { \
  const ushort* _p = (PTR) + (size_t)((RBASE) + srow) * 768 + ((KT) << 6) + scol; \
  __builtin_amdgcn_global_load_lds((const GLOBAL_AS void*)_p, \
      (LDS_AS void*)((LDS_AS ushort*)&lds[SL][RG][0] + (w << 9)), 16, 0, 0); \
  __builtin_amdgcn_global_load_lds((const GLOBAL_AS void*)(_p + (size_t)64 * 768), \
      (LDS_AS void*)((LDS_AS ushort*)&lds[SL][RG][0] + ((8 + w) << 9)), 16, 0, 0); \
} while (0)

__global__ __launch_bounds__(512, 1) void gemm_v3d(
    const ushort* __restrict__ A, const ushort* __restrict__ Bt,
    const float* __restrict__ bias,
    const void* __restrict__ resid, int rmode,
    void* __restrict__ C, int relu, int omode,
    const uint32_t* __restrict__ probe, int X) {
  __shared__ __align__(16) ushort lds[4][2][8192];   // 128 KiB
  const int bid  = blockIdx.x;
  const int tid  = threadIdx.x;
  const int lane = tid & 63, w = tid >> 6;            // w in 0..7
  const int wr = w >> 2, wc = w & 3;                  // 2M x 4N waves
  const int ml = lane & 15, kq = lane >> 4;
  const int rest = bid >> 3;
  const int x = rest % X, y = (bid & 7) + 8 * (rest / X);
  const int m0 = y << 7, n0 = x << 7;
  const int srow = (w << 3) + (lane >> 3);            // 0..63
  const int scol = (((lane & 7) ^ (lane >> 3)) << 3);
  const int swz  = (ml & 7) << 3;

  frag_cd acc[4][2] = {};
  frag_ab aF[4][2], bF[2][2];

  DSTG(0, 0, A, m0, 0); DSTG(0, 1, Bt, n0, 0);
  DSTG(1, 0, A, m0, 1); DSTG(1, 1, Bt, n0, 1);
  DSTG(2, 0, A, m0, 2); DSTG(2, 1, Bt, n0, 2);
  VMC8; BAR;

#pragma unroll 4
  for (int t = 0; t < 12; ++t) {
    const int sl  = t & 3;
    const int tn  = (t + 3 < 12) ? t + 3 : 11;   // clamped prefetch
    const int sln = (t + 3) & 3;
    DSTG(sln, 0, A, m0, tn); DSTG(sln, 1, Bt, n0, tn);
    VMC8;                       // tiles <= t+1 landed (per-wave)
    DRD_A(sl); DRD_B(sl);
    LGKM0;
    DMM();
    BAR;                        // publishes tile t+1 cross-wave; frees slot
  }

  const bool obf = (omode == 1) || (omode == 2 && probe_bf(probe));
  const bool rbf = (rmode == 2) && probe_bf(probe);
#pragma unroll
  for (int mt = 0; mt < 4; mt++) {
#pragma unroll
    for (int nt = 0; nt < 2; nt++) {
      const int row0 = m0 + wr * 64 + mt * 16 + kq * 4;
      const int col  = n0 + wc * 32 + nt * 16 + ml;
      const float bc = bias[col];
#pragma unroll
      for (int r = 0; r < 4; r++) {
        const size_t off = (size_t)(row0 + r) * 768 + col;
        float v = acc[mt][nt][r] + bc;
        if (rmode != 0)
          v += rbf ? bf2f(((const ushort*)resid)[off]) : ((const float*)resid)[off];
        if (relu) v = fmaxf(v, 0.f);
        if (obf) ((ushort*)C)[off] = f2bf(v);
        else     ((float*)C)[off]  = v;
      }
    }
  }
}

#undef DRD_A
#undef DRD_B
#undef DMM
#undef DSTG

// ---------------------------------------------------------------------------
// MFMA flash attention (R4-verified): double-buffered K/V LDS -> ONE barrier
// per KV-tile, + T14 reg prefetch. LDS 52 KB -> 3 blocks/CU.
// ---------------------------------------------------------------------------
#define FS 68
__global__ __launch_bounds__(256) void fattn_mfma(
    const ushort* __restrict__ Q, const ushort* __restrict__ Kp,
    const ushort* __restrict__ vT, ushort* __restrict__ O, int Skv) {
  __shared__ __align__(16) ushort Qs[64 * FS];
  __shared__ __align__(16) ushort Ks[2][64 * FS];
  __shared__ __align__(16) ushort Vt[2][64 * FS];
  __shared__ __align__(16) ushort Ps[64 * FS];
  const int tid  = threadIdx.x;
  const int lane = tid & 63, w = tid >> 6;
  const int ml   = lane & 15, kq = lane >> 4;
  const int bid = blockIdx.x;
  const int g8  = bid & 7;
  const int qt  = (bid >> 3) & 3;
  const int g   = (bid >> 5) * 8 + g8;      // 0..191 = b*12+h
  const int h   = g % HEADS;
  const int b   = g / HEADS;
  const int q0  = qt * 64;
  const ushort* Qb  = Q  + ((size_t)b * SP + q0) * D_MODEL + h * D_HEAD;
  const ushort* Kb  = Kp + (size_t)b * Skv * D_MODEL + h * D_HEAD;
  const ushort* vTb = vT + (size_t)g * 64 * Skv;

  const int r0 = tid >> 3, p0 = tid & 7;
  const int r1 = r0 + 32;

  for (int c = tid; c < 512; c += 256) {
    const int r = c >> 3, p = c & 7;
    *(uint4*)&Qs[r * FS + p * 8] = *(const uint4*)(Qb + (size_t)r * D_MODEL + p * 8);
  }

  uint4 kr0 = *(const uint4*)(Kb + (size_t)r0 * D_MODEL + p0 * 8);
  uint4 vr0 = *(const uint4*)(vTb + (size_t)r0 * Skv + p0 * 8);
  uint4 kr1 = *(const uint4*)(Kb + (size_t)r1 * D_MODEL + p0 * 8);
  uint4 vr1 = *(const uint4*)(vTb + (size_t)r1 * Skv + p0 * 8);
  *(uint4*)&Ks[0][r0 * FS + p0 * 8] = kr0;
  *(uint4*)&Vt[0][r0 * FS + p0 * 8] = vr0;
  *(uint4*)&Ks[0][r1 * FS + p0 * 8] = kr1;
  *(uint4*)&Vt[0][r1 * FS + p0 * 8] = vr1;
  __syncthreads();

  frag_ab qa[2];
#pragma unroll
  for (int kc = 0; kc < 2; kc++)
    qa[kc] = *(const frag_ab*)&Qs[(w * 16 + ml) * FS + kc * 32 + kq * 8];

  frag_cd oc[4] = {};
  float m_i[4], l_i[4];
#pragma unroll
  for (int r = 0; r < 4; r++) { m_i[r] = -1e30f; l_i[r] = 0.f; }
  const float SCL = 0.125f * 1.44269504f;
  const int NT = Skv >> 6;

  for (int t = 0; t < NT; ++t) {
    const int cb = t & 1;
    if (t + 1 < NT) {                      // T14: next tile -> regs early
      const int jn = (t + 1) << 6;
      kr0 = *(const uint4*)(Kb + (size_t)(jn + r0) * D_MODEL + p0 * 8);
      vr0 = *(const uint4*)(vTb + (size_t)r0 * Skv + jn + p0 * 8);
      kr1 = *(const uint4*)(Kb + (size_t)(jn + r1) * D_MODEL + p0 * 8);
      vr1 = *(const uint4*)(vTb + (size_t)r1 * Skv + jn + p0 * 8);
    }

    frag_cd sc[4] = {};
#pragma unroll
    for (int nt = 0; nt < 4; nt++)
#pragma unroll
      for (int kc = 0; kc < 2; kc++) {
        const frag_ab bfr = *(const frag_ab*)&Ks[cb][(nt * 16 + ml) * FS + kc * 32 + kq * 8];
        sc[nt] = __builtin_amdgcn_mfma_f32_16x16x32_bf16(qa[kc], bfr, sc[nt], 0, 0, 0);
      }
#pragma unroll
    for (int nt = 0; nt < 4; nt++)
#pragma unroll
      for (int r = 0; r < 4; r++) sc[nt][r] *= SCL;

    float al[4];
#pragma unroll
    for (int r = 0; r < 4; r++) {
      float mx = fmaxf(fmaxf(sc[0][r], sc[1][r]), fmaxf(sc[2][r], sc[3][r]));
#pragma unroll
      for (int m = 1; m < 16; m <<= 1) mx = fmaxf(mx, __shfl_xor(mx, m, 16));
      const float mnew = fmaxf(m_i[r], mx);
      al[r] = exp2f(m_i[r] - mnew);
      float p[4], s = 0.f;
#pragma unroll
      for (int nt = 0; nt < 4; nt++) { p[nt] = exp2f(sc[nt][r] - mnew); s += p[nt]; }
#pragma unroll
      for (int m = 1; m < 16; m <<= 1) s += __shfl_xor(s, m, 16);
      l_i[r] = l_i[r] * al[r] + s;
      m_i[r] = mnew;
      const int prow = (w * 16 + kq * 4 + r) * FS;
#pragma unroll
      for (int nt = 0; nt < 4; nt++) Ps[prow + nt * 16 + ml] = f2bf(p[nt]);
    }
#pragma unroll
    for (int dt = 0; dt < 4; dt++)
#pragma unroll
      for (int r = 0; r < 4; r++) oc[dt][r] *= al[r];

#pragma unroll
    for (int kc = 0; kc < 2; kc++) {
      const frag_ab pa = *(const frag_ab*)&Ps[(w * 16 + ml) * FS + kc * 32 + kq * 8];
#pragma unroll
      for (int dt = 0; dt < 4; dt++) {
        const frag_ab vb = *(const frag_ab*)&Vt[cb][(dt * 16 + ml) * FS + kc * 32 + kq * 8];
        oc[dt] = __builtin_amdgcn_mfma_f32_16x16x32_bf16(pa, vb, oc[dt], 0, 0, 0);
      }
    }

    if (t + 1 < NT) {
      *(uint4*)&Ks[cb ^ 1][r0 * FS + p0 * 8] = kr0;
      *(uint4*)&Vt[cb ^ 1][r0 * FS + p0 * 8] = vr0;
      *(uint4*)&Ks[cb ^ 1][r1 * FS + p0 * 8] = kr1;
      *(uint4*)&Vt[cb ^ 1][r1 * FS + p0 * 8] = vr1;
      __syncthreads();
    }
  }

  float inv[4];
#pragma unroll
  for (int r = 0; r < 4; r++) inv[r] = 1.0f / l_i[r];
#pragma unroll
  for (int dt = 0; dt < 4; dt++)
#pragma unroll
    for (int r = 0; r < 4; r++)
      O[((size_t)b * SP + q0 + w * 16 + kq * 4 + r) * D_MODEL + h * D_HEAD + dt * 16 + ml] =
          f2bf(oc[dt][r] * inv[r]);
}

// ---------------------------------------------------------------------------
extern "C" void kernel_launch(void* const* d_in, const int* in_sizes, int n_in,
                              void* d_out, int out_size, void* d_ws, size_t ws_size,
                              hipStream_t stream) {
  (void)in_sizes; (void)n_in; (void)out_size;
  char* base = (char*)d_ws;
  size_t off = 256;
  auto alloc = [&](size_t bytes) -> char* {
    char* p = base + off;
    off = (off + bytes + 255) & ~(size_t)255;
    return p;
  };
  const size_t WB = (size_t)768 * 768 * 2;
  ushort* Wt[10];
  for (int i = 0; i < 10; i++) Wt[i] = (ushort*)alloc(WB);   // contiguous
  float* vecs = (float*)alloc(18 * 768 * 4);                 // 10 bias + 8 ln
  float* biasF[10];
  for (int i = 0; i < 10; i++) biasF[i] = vecs + i * 768;
  float* lnF = vecs + 10 * 768;
  float* prompt0 = (float*)alloc((size_t)NP * 768 * 4);
  float* cur     = (float*)alloc((size_t)NP * 768 * 4);
  ushort* q_bf   = (ushort*)alloc((size_t)NP * 768 * 2);
  ushort* k_s    = (ushort*)alloc((size_t)NP * 768 * 2);
  ushort* k_c    = (ushort*)alloc((size_t)NI * 768 * 2);
  ushort* xln_bf = (ushort*)alloc((size_t)NP * 768 * 2);
  ushort* xi_bf  = (ushort*)alloc((size_t)NI * 768 * 2);
  ushort* obuf_bf = (ushort*)alloc((size_t)NP * 768 * 2);
  ushort* ffn1_bf = (ushort*)alloc((size_t)NP * 768 * 2);
  ushort* vT_s   = (ushort*)alloc((size_t)BATCH * HEADS * 64 * SP * 2);
  ushort* vT_c   = (ushort*)alloc((size_t)BATCH * HEADS * 64 * SI * 2);
  if (ws_size < off) return;

  const uint32_t* probe = (const uint32_t*)d_in[4];   // ln_p1_g
  const int widx[10] = {12, 14, 16, 18, 20, 22, 24, 26, 28, 30};
  const int bidx[10] = {13, 15, 17, 19, 21, 23, 25, 27, 29, 31};

  // 1. prep: weight transpose + param convert
  Prep pr{};
  for (int i = 0; i < 10; i++) { pr.wsrc[i] = d_in[widx[i]]; pr.wdst[i] = Wt[i]; }
  for (int i = 0; i < 10; i++) pr.vsrc[i] = d_in[bidx[i]];
  for (int i = 0; i < 8;  i++) pr.vsrc[10 + i] = d_in[4 + i];
  pr.vdst = vecs;
  prep_kernel<<<dim3(24, 24, 11), 256, 0, stream>>>(pr, probe);

  float* G1 = lnF + 0 * 768, *B1 = lnF + 1 * 768;   // ln_p1
  float* G2 = lnF + 2 * 768, *B2 = lnF + 3 * 768;   // ln_p2
  float* G3 = lnF + 4 * 768, *B3 = lnF + 5 * 768;   // ln_p3
  float* Gi = lnF + 6 * 768, *Bi = lnF + 7 * 768;   // ln_i1

  // 2. LN1(prompt+posp, sum->prompt0) + LNi(image+posi) merged, wave-per-row
  LNJob L0{d_in[1], d_in[3], G1, B1, prompt0, xln_bf, NP, 1};
  LNJob Li{d_in[0], d_in[2], Gi, Bi, nullptr, xi_bf,  NI, 1};
  add_ln_wave<<<(NP + NI) / 4, 256, 0, stream>>>(L0, Li, probe);

  // 3. mega GEMM (BK=32 deep pipeline, 2 blocks/CU): self QKV (576) +
  //    cross KV (1536).
  GJob js{xln_bf, Wt[0], biasF[0], q_bf, k_s, vT_s, 18, 2, 8};
  GJob jc{xi_bf,  Wt[5], biasF[5], k_c,  nullptr, vT_c, 12, 1, 10};
  gemm_mega32<<<576 + 1536, 512, 0, stream>>>(js, jc, 576);

  // 4. self flash attention
  fattn_mfma<<<BATCH * HEADS * (SP / 64), 256, 0, stream>>>(q_bf, k_s, vT_s, obuf_bf, SP);

  // 5. O-proj self: cur(fp32) = obuf@Wo + bo + prompt(input dtype)
  gemm_v3d<<<192, 512, 0, stream>>>(obuf_bf, Wt[3], biasF[3],
      d_in[1], 2, cur, 0, 0, probe, 6);

  // 6. LN2(cur + prompt0)
  LNJob L2{cur, prompt0, G2, B2, nullptr, xln_bf, NP, 0};
  LNJob Lz{}; Lz.nrows = 0;
  add_ln_wave<<<NP / 4, 256, 0, stream>>>(L2, Lz, probe);

  // 7. cross Q projection (bf16 out)
  gemm_v3d<<<192, 512, 0, stream>>>(xln_bf, Wt[4], biasF[4],
      nullptr, 0, q_bf, 0, 1, probe, 6);

  // 8. cross flash attention
  fattn_mfma<<<BATCH * HEADS * (SP / 64), 256, 0, stream>>>(q_bf, k_c, vT_c, obuf_bf, SI);

  // 9. O-proj cross: cur = obuf@Wo2 + bo2 + cur (fp32, in-place per-element)
  gemm_v3d<<<192, 512, 0, stream>>>(obuf_bf, Wt[7], biasF[7],
      cur, 1, cur, 0, 0, probe, 6);

  // 10. LN3(cur + prompt0)
  LNJob L3{cur, prompt0, G3, B3, nullptr, xln_bf, NP, 0};
  add_ln_wave<<<NP / 4, 256, 0, stream>>>(L3, Lz, probe);

  // 11. FFN1: relu(xln@W1+b1) -> bf16
  gemm_v3d<<<192, 512, 0, stream>>>(xln_bf, Wt[8], biasF[8],
      nullptr, 0, ffn1_bf, 1, 1, probe, 6);

  // 12. FFN2: d_out (dtype per probe)
  gemm_v3d<<<192, 512, 0, stream>>>(ffn1_bf, Wt[9], biasF[9],
      nullptr, 0, d_out, 0, 2, probe, 6);
}